// Round 5
// baseline (638.984 us; speedup 1.0000x reference)
//
#include <hip/hip_runtime.h>
#include <math.h>

#define N_AGENT 60000
#define N_MAP   40000
#define N_NODES 100000
#define NE      3200000
#define HID     32
#define PERIODS 30

#define NBUCK   391        // ceil(100000/256) buckets of 256 dst nodes
#define CAP     8704       // per-bucket capacity (mean 8184, sigma~90 -> +5.7 sigma)
#define TILE    4096       // edges per partition block
#define PTHREADS 512

// ---------------- kernel 0: fold weights, softmax sum, cursor init ----------------
__global__ void k_precompute(const float* Wz_c, const float* bz_c,
                             const float* Wh_c, const float* bh_c,
                             const float* Wz_l, const float* bz_l,
                             const float* Wh_l, const float* bh_l,
                             const float* attn,
                             float* Mz, float* Mh, float* bz_eff, float* bh_eff,
                             float* s_out, int* cursor) {
    int t = threadIdx.x;            // blockDim = 1024
    int k = t >> 5, c = t & 31;
    float mz = 0.f, mh = 0.f;
    for (int j = 0; j < HID; ++j) {
        mz += Wz_c[k * HID + j] * Wz_l[j * HID + c];   // Wz_l rows 0..31 (zeros half dead)
        mh += Wh_c[k * HID + j] * Wh_l[j * HID + c];
    }
    Mz[t] = mz; Mh[t] = mh;
    if (t < NBUCK) cursor[t] = t * CAP;
    if (t < HID) {
        float bz = bz_l[t], bh = bh_l[t];
        for (int j = 0; j < HID; ++j) {
            bz += bz_c[j] * Wz_l[j * HID + t];
            bh += bh_c[j] * Wh_l[j * HID + t];
        }
        bz_eff[t] = bz; bh_eff[t] = bh;
    }
    if (t == 0) {
        float m = -1e30f;
        for (int i = 0; i < PERIODS; ++i) m = fmaxf(m, attn[i]);
        float S = 0.f;
        for (int i = 0; i < PERIODS; ++i) S += expf(attn[i] - m);
        float s = 0.f;
        for (int i = 0; i < PERIODS; ++i) s += expf(attn[i] - m) / S;
        *s_out = s;
    }
}

// ---------------- kernel 1: node encoders ----------------
__global__ void k_encode(const float* __restrict__ agent_x, const float* __restrict__ map_x,
                         const float* __restrict__ W_agent, const float* __restrict__ b_agent,
                         const float* __restrict__ W_map, const float* __restrict__ b_map,
                         float* __restrict__ x) {
    int t = blockIdx.x * blockDim.x + threadIdx.x;
    if (t >= N_NODES * HID) return;
    int i = t >> 5, c = t & 31;
    float acc;
    if (i < N_AGENT) {
        const float* row = agent_x + (size_t)i * 9;
        acc = b_agent[c];
#pragma unroll
        for (int k = 0; k < 9; ++k) acc += row[k] * W_agent[k * HID + c];
    } else {
        const float* row = map_x + (size_t)(i - N_AGENT) * 6;
        acc = b_map[c];
#pragma unroll
        for (int k = 0; k < 6; ++k) acc += row[k] * W_map[k * HID + c];
    }
    x[t] = acc;
}

// ---------------- kernel 2: LDS-staged partition (multisplit) ----------------
// pack = src | (dst_low << 17); bucket = dst >> 8
__global__ __launch_bounds__(PTHREADS) void k_partition(
        const int* __restrict__ src, const int* __restrict__ dst,
        int* __restrict__ cursor, int* __restrict__ ebuf) {
    __shared__ int sCnt[NBUCK + 1];
    __shared__ int sBase[NBUCK + 1];
    __shared__ int sGbase[NBUCK];
    __shared__ int sScan[PTHREADS];
    __shared__ int sReorder[TILE];
    int t = threadIdx.x;
    int tileBase = blockIdx.x * TILE;
    int tcount = NE - tileBase; if (tcount > TILE) tcount = TILE;

    if (t < NBUCK) sCnt[t] = 0;
    __syncthreads();

    int pb[8]; int pp[8];
#pragma unroll
    for (int k = 0; k < 8; ++k) {
        int e = tileBase + t + k * PTHREADS;
        pb[k] = -1;
        if (e < NE) {
            int s = src[e], d = dst[e];
            pb[k] = d >> 8;
            pp[k] = s | ((d & 255) << 17);
            atomicAdd(&sCnt[pb[k]], 1);
        }
    }
    __syncthreads();

    // inclusive scan of sCnt via sScan (Hillis-Steele over 512 threads)
    int v = (t < NBUCK) ? sCnt[t] : 0;
    sScan[t] = v;
    __syncthreads();
    for (int s = 1; s < PTHREADS; s <<= 1) {
        int a = (t >= s) ? sScan[t - s] : 0;
        __syncthreads();
        sScan[t] += a;
        __syncthreads();
    }
    if (t <= NBUCK) sBase[t] = sScan[t] - v;   // exclusive; sBase[NBUCK] = tile total
    __syncthreads();
    // reserve global space, reset counters for rank pass
    if (t < NBUCK) {
        if (sCnt[t] > 0) sGbase[t] = atomicAdd(&cursor[t], sCnt[t]);
        sCnt[t] = 0;
    }
    __syncthreads();
    // rank + reorder in LDS
#pragma unroll
    for (int k = 0; k < 8; ++k) {
        if (pb[k] >= 0) {
            int r = atomicAdd(&sCnt[pb[k]], 1);
            sReorder[sBase[pb[k]] + r] = pp[k];
        }
    }
    __syncthreads();
    // coalesced flush: binary-search bucket owning slot j
#pragma unroll
    for (int k = 0; k < 8; ++k) {
        int j = t + k * PTHREADS;
        if (j < tcount) {
            int lo = 0, hi = NBUCK;
            while (hi - lo > 1) {
                int m = (lo + hi) >> 1;
                if (sBase[m] <= j) lo = m; else hi = m;
            }
            ebuf[sGbase[lo] + (j - sBase[lo])] = sReorder[j];
        }
    }
}

// ---------------- kernel 3: per-bucket degree histogram -> dinv ----------------
__global__ __launch_bounds__(256) void k_hist(const int* __restrict__ cursor,
                                              const int* __restrict__ ebuf,
                                              float* __restrict__ dinv) {
    __shared__ int h[256];
    int t = threadIdx.x;
    int b = blockIdx.x;
    h[t] = 0;
    __syncthreads();
    int start = b * CAP;
    int cnt = cursor[b] - start;
    for (int j = t; j < cnt; j += 256)
        atomicAdd(&h[(ebuf[start + j] >> 17) & 255], 1);
    __syncthreads();
    int node = b * 256 + t;
    if (node < N_NODES) dinv[node] = rsqrtf((float)h[t] + 1.0f);
}

// ---------------- kernel 4: sub-bucket aggregation (no global atomics) ----------------
// Block (b, sub) owns 32 dst rows [b*256+sub*32, +32). It scans bucket b's
// packed slice with coalesced 128B loads (8x redundant scan, L2-hot), keeps
// edges whose dl falls in its slice via ballot-compact, gathers x/dinv, and
// accumulates into a 4KB LDS acc. Rows are exclusive -> plain stores to agg.
__global__ __launch_bounds__(256) void k_agg(
        const int* __restrict__ cursor, const int* __restrict__ ebuf,
        const float* __restrict__ dinv, const float* __restrict__ x,
        float* __restrict__ agg) {
    __shared__ float acc[32 * 32];          // 4 KB
    int t = threadIdx.x;
    for (int j = t; j < 1024; j += 256) acc[j] = 0.f;
    __syncthreads();

    const int b   = blockIdx.x >> 3;        // bucket 0..234
    const int sub = blockIdx.x & 7;         // 32-row slice within bucket
    const int c = t & 31;
    const int g = t >> 5;                   // 8 groups of 32 lanes
    const int half = (g & 1) * 32;          // position of this group in its wave64
    const int start = b * CAP;
    const int cnt = cursor[b] - start;
    const int dlo = sub * 32, dhi = dlo + 32;

    for (int jb = g * 32; jb < cnt; jb += 8 * 32) {
        int idx = jb + c;
        int p = (idx < cnt) ? ebuf[start + idx] : -1;   // coalesced 128B per group
        int dl = (p >> 17) & 255;
        bool match = (p >= 0) && (dl >= dlo) && (dl < dhi);
        unsigned mask = (unsigned)(__ballot(match) >> half);
        while (mask) {
            int bit = __ffs(mask) - 1;
            mask &= mask - 1;
            int pk = __shfl(p, bit, 32);
            int sk = pk & 0x1FFFF;
            int rw = (pk >> 17) & 31;       // row within slice (dlo is mult of 32)
            float v = x[(size_t)sk * HID + c] * dinv[sk];
            atomicAdd(&acc[rw * 32 + c], v);
        }
    }
    __syncthreads();

    // write exclusive rows + self-loop term
    const int nodeBase = b * 256 + dlo;
    for (int r = g; r < 32; r += 8) {
        int i = nodeBase + r;
        if (i >= N_AGENT) break;
        float di = dinv[i];
        agg[(size_t)i * HID + c] = (acc[r * 32 + c] + x[(size_t)i * HID + c] * di) * di;
    }
}

// ---------------- kernel 5: gates + MLP per agent node ----------------
__global__ __launch_bounds__(1024) void k_out(
        const float* __restrict__ agg,
        const float* __restrict__ Mz, const float* __restrict__ Mh,
        const float* __restrict__ bz_eff, const float* __restrict__ bh_eff,
        const float* __restrict__ s_ptr,
        const float* __restrict__ W1, const float* __restrict__ b1,
        const float* __restrict__ W2, const float* __restrict__ b2,
        float* __restrict__ out) {
    __shared__ float sMz[1024], sMh[1024], sW1[2048], sW2[6400];
    __shared__ float sbz[32], sbh[32], sb1[64], sb2[100];
    int t = threadIdx.x;
    sMz[t] = Mz[t]; sMh[t] = Mh[t];
    for (int j = t; j < 2048; j += 1024) sW1[j] = W1[j];
    for (int j = t; j < 6400; j += 1024) sW2[j] = W2[j];
    if (t < 32) { sbz[t] = bz_eff[t]; sbh[t] = bh_eff[t]; }
    if (t >= 32 && t < 96) sb1[t - 32] = b1[t - 32];
    if (t >= 128 && t < 228) sb2[t - 128] = b2[t - 128];
    __syncthreads();

    const float s = *s_ptr;
    const int c = t & 31;
    const int g = t >> 5;               // 32 groups
    const int nodeBase = blockIdx.x * 256;
    for (int r = g; r < 256; r += 32) {
        int i = nodeBase + r;
        if (i >= N_AGENT) break;
        float a = agg[(size_t)i * HID + c];
        float uz = sbz[c], uh = sbh[c];
#pragma unroll
        for (int k = 0; k < 32; ++k) {
            float ak = __shfl(a, k, 32);
            uz += ak * sMz[k * 32 + c];
            uh += ak * sMh[k * 32 + c];
        }
        float z = 1.0f / (1.0f + expf(-uz));
        float h = s * (1.0f - z) * tanhf(uh);
        h = fmaxf(h, 0.0f);
        float t0 = sb1[c], t1 = sb1[c + 32];
#pragma unroll
        for (int k = 0; k < 32; ++k) {
            float hk = __shfl(h, k, 32);
            t0 += hk * sW1[k * 64 + c];
            t1 += hk * sW1[k * 64 + c + 32];
        }
        t0 = fmaxf(t0, 0.0f); t1 = fmaxf(t1, 0.0f);
        int j3 = (c < 4) ? (c + 96) : 99;
        float o0 = sb2[c];
        float o1 = sb2[c + 32];
        float o2 = sb2[c + 64];
        float o3 = sb2[j3];
#pragma unroll
        for (int k = 0; k < 32; ++k) {
            float ta = __shfl(t0, k, 32);
            float tb = __shfl(t1, k, 32);
            o0 += ta * sW2[k * 100 + c]      + tb * sW2[(k + 32) * 100 + c];
            o1 += ta * sW2[k * 100 + c + 32] + tb * sW2[(k + 32) * 100 + c + 32];
            o2 += ta * sW2[k * 100 + c + 64] + tb * sW2[(k + 32) * 100 + c + 64];
            o3 += ta * sW2[k * 100 + j3]     + tb * sW2[(k + 32) * 100 + j3];
        }
        float* orow = out + (size_t)i * 100;
        orow[c] = o0;
        orow[c + 32] = o1;
        orow[c + 64] = o2;
        if (c < 4) orow[c + 96] = o3;
    }
}

extern "C" void kernel_launch(void* const* d_in, const int* in_sizes, int n_in,
                              void* d_out, int out_size, void* d_ws, size_t ws_size,
                              hipStream_t stream) {
    const float* agent_x = (const float*)d_in[0];
    const float* map_x   = (const float*)d_in[1];
    const int*   ei      = (const int*)d_in[2];
    const float* W_agent = (const float*)d_in[3];
    const float* b_agent = (const float*)d_in[4];
    const float* W_map   = (const float*)d_in[5];
    const float* b_map   = (const float*)d_in[6];
    const float* Wz_c    = (const float*)d_in[7];
    const float* bz_c    = (const float*)d_in[8];
    const float* Wh_c    = (const float*)d_in[11];
    const float* bh_c    = (const float*)d_in[12];
    const float* Wz_l    = (const float*)d_in[13];
    const float* bz_l    = (const float*)d_in[14];
    const float* Wh_l    = (const float*)d_in[17];
    const float* bh_l    = (const float*)d_in[18];
    const float* attn    = (const float*)d_in[19];
    const float* W1      = (const float*)d_in[20];
    const float* b1      = (const float*)d_in[21];
    const float* W2      = (const float*)d_in[22];
    const float* b2      = (const float*)d_in[23];
    float* out = (float*)d_out;

    const int* e_src = ei;
    const int* e_dst = ei + NE;

    // workspace layout (float-element offsets); total 34.50 MB (R2 proved >= 34.57 MB)
    float* ws     = (float*)d_ws;
    float* x      = ws;                         // 3,200,000
    float* Mz     = ws + 3200000;               // 1024
    float* Mh     = ws + 3201024;               // 1024
    float* bz     = ws + 3202048;               // 32
    float* bh     = ws + 3202080;               // 32
    float* sS     = ws + 3202112;               // 1 (pad to 3202304)
    float* dinv   = ws + 3202304;               // 100,000 (pad to 3302400)
    int*   cursor = (int*)(ws + 3302400);       // 391 (pad 512)
    float* agg    = ws + 3302912;               // 1,920,000 -> 5,222,912
    int*   ebuf   = (int*)(ws + 5222912);       // NBUCK*CAP = 3,403,264 -> end 8,626,176

    k_precompute<<<1, 1024, 0, stream>>>(Wz_c, bz_c, Wh_c, bh_c, Wz_l, bz_l,
                                         Wh_l, bh_l, attn, Mz, Mh, bz, bh, sS, cursor);
    k_encode<<<(N_NODES * HID + 255) / 256, 256, 0, stream>>>(
        agent_x, map_x, W_agent, b_agent, W_map, b_map, x);
    k_partition<<<(NE + TILE - 1) / TILE, PTHREADS, 0, stream>>>(e_src, e_dst, cursor, ebuf);
    k_hist<<<NBUCK, 256, 0, stream>>>(cursor, ebuf, dinv);
    k_agg<<<235 * 8, 256, 0, stream>>>(cursor, ebuf, dinv, x, agg);
    k_out<<<235, 1024, 0, stream>>>(agg, Mz, Mh, bz, bh, sS, W1, b1, W2, b2, out);
}

// Round 6
// 630.458 us; speedup vs baseline: 1.0135x; 1.0135x over previous
//
#include <hip/hip_runtime.h>
#include <math.h>

#define N_AGENT 60000
#define N_MAP   40000
#define N_NODES 100000
#define NE      3200000
#define HID     32
#define PERIODS 30

#define NBUCK   391        // ceil(100000/256) buckets of 256 dst nodes
#define CAP     8704       // per-bucket capacity (mean 8184, +5.7 sigma)
#define TILE    4096       // edges per partition block
#define PTHREADS 512

// ---------------- kernel 0: fold weights, softmax sum, cursor init ----------------
__global__ void k_precompute(const float* Wz_c, const float* bz_c,
                             const float* Wh_c, const float* bh_c,
                             const float* Wz_l, const float* bz_l,
                             const float* Wh_l, const float* bh_l,
                             const float* attn,
                             float* Mz, float* Mh, float* bz_eff, float* bh_eff,
                             float* s_out, int* cursor) {
    int t = threadIdx.x;            // blockDim = 1024
    int k = t >> 5, c = t & 31;
    float mz = 0.f, mh = 0.f;
    for (int j = 0; j < HID; ++j) {
        mz += Wz_c[k * HID + j] * Wz_l[j * HID + c];   // Wz_l rows 0..31 (zeros half dead)
        mh += Wh_c[k * HID + j] * Wh_l[j * HID + c];
    }
    Mz[t] = mz; Mh[t] = mh;
    if (t < NBUCK) cursor[t] = t * CAP;
    if (t < HID) {
        float bz = bz_l[t], bh = bh_l[t];
        for (int j = 0; j < HID; ++j) {
            bz += bz_c[j] * Wz_l[j * HID + t];
            bh += bh_c[j] * Wh_l[j * HID + t];
        }
        bz_eff[t] = bz; bh_eff[t] = bh;
    }
    if (t == 0) {
        float m = -1e30f;
        for (int i = 0; i < PERIODS; ++i) m = fmaxf(m, attn[i]);
        float S = 0.f;
        for (int i = 0; i < PERIODS; ++i) S += expf(attn[i] - m);
        float s = 0.f;
        for (int i = 0; i < PERIODS; ++i) s += expf(attn[i] - m) / S;
        *s_out = s;
    }
}

// ---------------- kernel 1: node encoders ----------------
__global__ void k_encode(const float* __restrict__ agent_x, const float* __restrict__ map_x,
                         const float* __restrict__ W_agent, const float* __restrict__ b_agent,
                         const float* __restrict__ W_map, const float* __restrict__ b_map,
                         float* __restrict__ x) {
    int t = blockIdx.x * blockDim.x + threadIdx.x;
    if (t >= N_NODES * HID) return;
    int i = t >> 5, c = t & 31;
    float acc;
    if (i < N_AGENT) {
        const float* row = agent_x + (size_t)i * 9;
        acc = b_agent[c];
#pragma unroll
        for (int k = 0; k < 9; ++k) acc += row[k] * W_agent[k * HID + c];
    } else {
        const float* row = map_x + (size_t)(i - N_AGENT) * 6;
        acc = b_map[c];
#pragma unroll
        for (int k = 0; k < 6; ++k) acc += row[k] * W_map[k * HID + c];
    }
    x[t] = acc;
}

// ---------------- kernel 2: LDS-staged partition (multisplit) ----------------
// pack = src | (dst_low << 17); bucket = dst >> 8
__global__ __launch_bounds__(PTHREADS) void k_partition(
        const int* __restrict__ src, const int* __restrict__ dst,
        int* __restrict__ cursor, int* __restrict__ ebuf) {
    __shared__ int sCnt[NBUCK + 1];
    __shared__ int sBase[NBUCK + 1];
    __shared__ int sGbase[NBUCK];
    __shared__ int sScan[PTHREADS];
    __shared__ int sReorder[TILE];
    int t = threadIdx.x;
    int tileBase = blockIdx.x * TILE;
    int tcount = NE - tileBase; if (tcount > TILE) tcount = TILE;

    if (t < NBUCK) sCnt[t] = 0;
    __syncthreads();

    int pb[8]; int pp[8];
#pragma unroll
    for (int k = 0; k < 8; ++k) {
        int e = tileBase + t + k * PTHREADS;
        pb[k] = -1;
        if (e < NE) {
            int s = src[e], d = dst[e];
            pb[k] = d >> 8;
            pp[k] = s | ((d & 255) << 17);
            atomicAdd(&sCnt[pb[k]], 1);
        }
    }
    __syncthreads();

    // inclusive scan of sCnt via sScan (Hillis-Steele over 512 threads)
    int v = (t < NBUCK) ? sCnt[t] : 0;
    sScan[t] = v;
    __syncthreads();
    for (int s = 1; s < PTHREADS; s <<= 1) {
        int a = (t >= s) ? sScan[t - s] : 0;
        __syncthreads();
        sScan[t] += a;
        __syncthreads();
    }
    if (t <= NBUCK) sBase[t] = sScan[t] - v;   // exclusive; sBase[NBUCK] = tile total
    __syncthreads();
    // reserve global space, reset counters for rank pass
    if (t < NBUCK) {
        if (sCnt[t] > 0) sGbase[t] = atomicAdd(&cursor[t], sCnt[t]);
        sCnt[t] = 0;
    }
    __syncthreads();
    // rank + reorder in LDS
#pragma unroll
    for (int k = 0; k < 8; ++k) {
        if (pb[k] >= 0) {
            int r = atomicAdd(&sCnt[pb[k]], 1);
            sReorder[sBase[pb[k]] + r] = pp[k];
        }
    }
    __syncthreads();
    // coalesced flush: binary-search bucket owning slot j
#pragma unroll
    for (int k = 0; k < 8; ++k) {
        int j = t + k * PTHREADS;
        if (j < tcount) {
            int lo = 0, hi = NBUCK;
            while (hi - lo > 1) {
                int m = (lo + hi) >> 1;
                if (sBase[m] <= j) lo = m; else hi = m;
            }
            ebuf[sGbase[lo] + (j - sBase[lo])] = sReorder[j];
        }
    }
}

// ---------------- kernel 3: per-bucket degree histogram -> dinv ----------------
__global__ __launch_bounds__(256) void k_hist(const int* __restrict__ cursor,
                                              const int* __restrict__ ebuf,
                                              float* __restrict__ dinv) {
    __shared__ int h[256];
    int t = threadIdx.x;
    int b = blockIdx.x;
    h[t] = 0;
    __syncthreads();
    int start = b * CAP;
    int cnt = cursor[b] - start;
    for (int j = t; j < cnt; j += 256)
        atomicAdd(&h[(ebuf[start + j] >> 17) & 255], 1);
    __syncthreads();
    int node = b * 256 + t;
    if (node < N_NODES) dinv[node] = rsqrtf((float)h[t] + 1.0f);
}

// ---------------- kernel 4: in-LDS 8-way sub-sort of each agent bucket ----------------
// Sorts bucket b's segment by dl>>5 (8 sub-slices of 32 dst rows), drops
// map-dst edges (bucket 234 tail), writes back in place + per-sub counts.
__global__ __launch_bounds__(512) void k_sub(const int* __restrict__ cursor,
                                             int* __restrict__ ebuf,
                                             int* __restrict__ scnt) {
    __shared__ int sRaw[CAP];        // 34.8 KB
    __shared__ int sSorted[CAP];     // 34.8 KB
    __shared__ int h[8], hb[8], hc[8];
    int t = threadIdx.x;
    int b = blockIdx.x;              // 0..234
    int start = b * CAP;
    int cnt = cursor[b] - start;
    if (t < 8) { h[t] = 0; hc[t] = 0; }
    __syncthreads();
    for (int j = t; j < cnt; j += 512) {
        int p = ebuf[start + j];
        sRaw[j] = p;
        int dl = (p >> 17) & 255;
        if (b * 256 + dl < N_AGENT) atomicAdd(&h[dl >> 5], 1);
    }
    __syncthreads();
    if (t == 0) { int s = 0; for (int k = 0; k < 8; ++k) { hb[k] = s; s += h[k]; } }
    __syncthreads();
    for (int j = t; j < cnt; j += 512) {
        int p = sRaw[j];
        int dl = (p >> 17) & 255;
        if (b * 256 + dl < N_AGENT) {
            int k = dl >> 5;
            int pos = hb[k] + atomicAdd(&hc[k], 1);
            sSorted[pos] = p;
        }
    }
    __syncthreads();
    int kept = hb[7] + h[7];
    for (int j = t; j < kept; j += 512) ebuf[start + j] = sSorted[j];
    if (t < 8) scnt[b * 8 + t] = h[t];
}

// ---------------- kernel 5: sub-slice aggregation, quad-batched float4 gathers ----
// Block (b,sub) owns 32 dst rows; scans its contiguous sub-slice once.
// Per 32-lane group: 32 packed edges coalesced, then 8 quad-batches — lane c
// handles edge (c>>3) of the quad and loads float4 channels (c&7)*4.. of
// x[src]: one wave64 load inst = 1 KB = 8 edge rows; all 8 quads prefetched
// before LDS atomics -> ~8 KB in flight per wave.
__global__ __launch_bounds__(256) void k_agg(
        const int* __restrict__ scnt, const int* __restrict__ ebuf,
        const float* __restrict__ dinv, const float* __restrict__ x,
        float* __restrict__ agg) {
    __shared__ float acc[32 * 32];          // 4 KB
    int t = threadIdx.x;
    const int sb = blockIdx.x;
    const int b = sb >> 3, sub = sb & 7;
    const int nodeBase = b * 256 + sub * 32;
    if (nodeBase >= N_AGENT) return;        // uniform per block (bucket-234 tail)
    for (int j = t; j < 1024; j += 256) acc[j] = 0.f;

    int pre = 0, cnt = 0;
#pragma unroll
    for (int k = 0; k < 8; ++k) {
        int v = scnt[b * 8 + k];
        if (k < sub) pre += v;
        if (k == sub) cnt = v;
    }
    const int start = b * CAP + pre;
    __syncthreads();

    const int c = t & 31;
    const int g = t >> 5;                   // 8 groups of 32 lanes
    const int ch = (c & 7) * 4;             // this lane's 4 channels
    const int eq = c >> 3;                  // this lane's edge within a quad

    for (int jb = g * 32; jb < cnt; jb += 8 * 32) {
        int idx = jb + c;
        int p = (idx < cnt) ? ebuf[start + idx] : -1;   // coalesced 128B per group
        float  qw[8];
        float4 qx[8];
        int    qrw[8], qok[8];
#pragma unroll
        for (int u = 0; u < 8; ++u) {
            int pk = __shfl(p, u * 4 + eq, 32);
            qok[u] = pk >= 0;
            int sk = qok[u] ? (pk & 0x1FFFF) : 0;
            qrw[u] = (pk >> 17) & 31;
            qw[u] = dinv[sk];
            qx[u] = *(const float4*)&x[(size_t)sk * HID + ch];
        }
#pragma unroll
        for (int u = 0; u < 8; ++u) {
            if (qok[u]) {
                float w = qw[u];
                int ab = qrw[u] * 32 + ch;
                atomicAdd(&acc[ab + 0], qx[u].x * w);
                atomicAdd(&acc[ab + 1], qx[u].y * w);
                atomicAdd(&acc[ab + 2], qx[u].z * w);
                atomicAdd(&acc[ab + 3], qx[u].w * w);
            }
        }
    }
    __syncthreads();

    // write exclusive rows + self-loop term
    for (int r = g; r < 32; r += 8) {
        int i = nodeBase + r;
        if (i >= N_AGENT) break;
        float di = dinv[i];
        agg[(size_t)i * HID + c] = (acc[r * 32 + c] + x[(size_t)i * HID + c] * di) * di;
    }
}

// ---------------- kernel 6: gates + MLP per agent node ----------------
__global__ __launch_bounds__(1024) void k_out(
        const float* __restrict__ agg,
        const float* __restrict__ Mz, const float* __restrict__ Mh,
        const float* __restrict__ bz_eff, const float* __restrict__ bh_eff,
        const float* __restrict__ s_ptr,
        const float* __restrict__ W1, const float* __restrict__ b1,
        const float* __restrict__ W2, const float* __restrict__ b2,
        float* __restrict__ out) {
    __shared__ float sMz[1024], sMh[1024], sW1[2048], sW2[6400];
    __shared__ float sbz[32], sbh[32], sb1[64], sb2[100];
    int t = threadIdx.x;
    sMz[t] = Mz[t]; sMh[t] = Mh[t];
    for (int j = t; j < 2048; j += 1024) sW1[j] = W1[j];
    for (int j = t; j < 6400; j += 1024) sW2[j] = W2[j];
    if (t < 32) { sbz[t] = bz_eff[t]; sbh[t] = bh_eff[t]; }
    if (t >= 32 && t < 96) sb1[t - 32] = b1[t - 32];
    if (t >= 128 && t < 228) sb2[t - 128] = b2[t - 128];
    __syncthreads();

    const float s = *s_ptr;
    const int c = t & 31;
    const int g = t >> 5;               // 32 groups
    const int nodeBase = blockIdx.x * 256;
    for (int r = g; r < 256; r += 32) {
        int i = nodeBase + r;
        if (i >= N_AGENT) break;
        float a = agg[(size_t)i * HID + c];
        float uz = sbz[c], uh = sbh[c];
#pragma unroll
        for (int k = 0; k < 32; ++k) {
            float ak = __shfl(a, k, 32);
            uz += ak * sMz[k * 32 + c];
            uh += ak * sMh[k * 32 + c];
        }
        float z = 1.0f / (1.0f + expf(-uz));
        float h = s * (1.0f - z) * tanhf(uh);
        h = fmaxf(h, 0.0f);
        float t0 = sb1[c], t1 = sb1[c + 32];
#pragma unroll
        for (int k = 0; k < 32; ++k) {
            float hk = __shfl(h, k, 32);
            t0 += hk * sW1[k * 64 + c];
            t1 += hk * sW1[k * 64 + c + 32];
        }
        t0 = fmaxf(t0, 0.0f); t1 = fmaxf(t1, 0.0f);
        int j3 = (c < 4) ? (c + 96) : 99;
        float o0 = sb2[c];
        float o1 = sb2[c + 32];
        float o2 = sb2[c + 64];
        float o3 = sb2[j3];
#pragma unroll
        for (int k = 0; k < 32; ++k) {
            float ta = __shfl(t0, k, 32);
            float tb = __shfl(t1, k, 32);
            o0 += ta * sW2[k * 100 + c]      + tb * sW2[(k + 32) * 100 + c];
            o1 += ta * sW2[k * 100 + c + 32] + tb * sW2[(k + 32) * 100 + c + 32];
            o2 += ta * sW2[k * 100 + c + 64] + tb * sW2[(k + 32) * 100 + c + 64];
            o3 += ta * sW2[k * 100 + j3]     + tb * sW2[(k + 32) * 100 + j3];
        }
        float* orow = out + (size_t)i * 100;
        orow[c] = o0;
        orow[c + 32] = o1;
        orow[c + 64] = o2;
        if (c < 4) orow[c + 96] = o3;
    }
}

extern "C" void kernel_launch(void* const* d_in, const int* in_sizes, int n_in,
                              void* d_out, int out_size, void* d_ws, size_t ws_size,
                              hipStream_t stream) {
    const float* agent_x = (const float*)d_in[0];
    const float* map_x   = (const float*)d_in[1];
    const int*   ei      = (const int*)d_in[2];
    const float* W_agent = (const float*)d_in[3];
    const float* b_agent = (const float*)d_in[4];
    const float* W_map   = (const float*)d_in[5];
    const float* b_map   = (const float*)d_in[6];
    const float* Wz_c    = (const float*)d_in[7];
    const float* bz_c    = (const float*)d_in[8];
    const float* Wh_c    = (const float*)d_in[11];
    const float* bh_c    = (const float*)d_in[12];
    const float* Wz_l    = (const float*)d_in[13];
    const float* bz_l    = (const float*)d_in[14];
    const float* Wh_l    = (const float*)d_in[17];
    const float* bh_l    = (const float*)d_in[18];
    const float* attn    = (const float*)d_in[19];
    const float* W1      = (const float*)d_in[20];
    const float* b1      = (const float*)d_in[21];
    const float* W2      = (const float*)d_in[22];
    const float* b2      = (const float*)d_in[23];
    float* out = (float*)d_out;

    const int* e_src = ei;
    const int* e_dst = ei + NE;

    // workspace layout (float-element offsets); total 34.51 MB (<= 34.57 proven)
    float* ws     = (float*)d_ws;
    float* x      = ws;                         // 3,200,000
    float* Mz     = ws + 3200000;               // 1024
    float* Mh     = ws + 3201024;               // 1024
    float* bz     = ws + 3202048;               // 32
    float* bh     = ws + 3202080;               // 32
    float* sS     = ws + 3202112;               // 1 (pad to 3202304)
    float* dinv   = ws + 3202304;               // 100,000 (pad to 3302400)
    int*   cursor = (int*)(ws + 3302400);       // 391 (pad 512)
    float* agg    = ws + 3302912;               // 1,920,000 -> 5,222,912
    int*   ebuf   = (int*)(ws + 5222912);       // NBUCK*CAP = 3,403,264 -> 8,626,176
    int*   scnt   = (int*)(ws + 8626176);       // 235*8 = 1880 -> end 8,628,056

    k_precompute<<<1, 1024, 0, stream>>>(Wz_c, bz_c, Wh_c, bh_c, Wz_l, bz_l,
                                         Wh_l, bh_l, attn, Mz, Mh, bz, bh, sS, cursor);
    k_encode<<<(N_NODES * HID + 255) / 256, 256, 0, stream>>>(
        agent_x, map_x, W_agent, b_agent, W_map, b_map, x);
    k_partition<<<(NE + TILE - 1) / TILE, PTHREADS, 0, stream>>>(e_src, e_dst, cursor, ebuf);
    k_hist<<<NBUCK, 256, 0, stream>>>(cursor, ebuf, dinv);
    k_sub<<<235, 512, 0, stream>>>(cursor, ebuf, scnt);
    k_agg<<<235 * 8, 256, 0, stream>>>(scnt, ebuf, dinv, x, agg);
    k_out<<<235, 1024, 0, stream>>>(agg, Mz, Mh, bz, bh, sS, W1, b1, W2, b2, out);
}